// Round 3
// baseline (31.106 us; speedup 1.0000x reference)
//
#include <hip/hip_runtime.h>

#define PI_F 3.14159265358979323846f

constexpr int ED = 128;           // embed_dim
constexpr int NCHARS = 95;
constexpr int ROWS_PER_BLOCK = 4; // 256 threads = 4 waves, 1 wave per row

// ws layout: float2 tbl[95*128] at byte 0 (97,280 B);
//            float  pp[S]       at byte 98,304 (S*4 B)
constexpr size_t PP_OFF = 98304;

__global__ __launch_bounds__(256) void build_tables(
    const int* __restrict__ positions,
    const float* __restrict__ W,
    float2* __restrict__ tbl,
    float* __restrict__ pp,
    int S)
{
    const int i = blockIdx.x * 256 + threadIdx.x;
    if (i < NCHARS * ED) {
        const int c = i >> 7;          // i / 128
        const int j = i & (ED - 1);
        const float* p = W + c * 8;
        const float omega = p[0] * 2.0f;
        const float A1 = p[1], A2 = p[2], A3 = p[3];
        const float beta = p[4];
        const float gamma = 1.0f / (1.0f + expf(-p[5]));  // sigmoid
        const float phi = p[6] * PI_F;
        const float fj = (float)j;
        const float base = (A1 * sinf(omega * fj + phi)
                          + A2 * sinf(2.0f * omega * fj + 2.0f * phi)
                          + A3 * sinf(3.0f * omega * fj + 3.0f * phi))
                         * expf(-gamma * fj);
        tbl[i] = make_float2(base, beta * fj);
    }
    if (i < S) {
        pp[i] = sinf((float)positions[i] * (0.1f * PI_F));
    }
}

__global__ __launch_bounds__(256) void ptok_main(
    const int* __restrict__ char_idx,
    const float2* __restrict__ tbl,
    const float* __restrict__ pp,
    float* __restrict__ out,
    int S)
{
    const int lane = threadIdx.x & 63;
    const int wv = threadIdx.x >> 6;                    // 0..3
    const int row = blockIdx.x * ROWS_PER_BLOCK + wv;   // b*S + s
    const int s = row & (S - 1);                        // S = 8192 (pow2)

    const int c = char_idx[row];                        // wave-uniform
    const float pp_s = pp[s];                           // wave-uniform

    const float2 t0 = tbl[c * ED + lane];
    const float2 t1 = tbl[c * ED + 64 + lane];
    const float w0 = fmaf(t0.y, pp_s, t0.x);
    const float w1 = fmaf(t1.y, pp_s, t1.x);

    // roll(wave,1): prev[j] = wave[(j-1) & 127]
    const int lm1 = (lane + 63) & 63;
    const float u0 = __shfl(w0, lm1, 64);
    const float u1 = __shfl(w1, lm1, 64);
    const float prev0 = (lane == 0) ? u1 : u0;  // j=0   -> wave[127]
    const float prev1 = (lane == 0) ? u0 : u1;  // j=64  -> wave[63]

    float4* orow = reinterpret_cast<float4*>(out) + (size_t)row * ED;
    float4 o0, o1;
    o0.x = w0; o0.y = prev0; o0.z = __sinf(w0); o0.w = __cosf(w0);
    o1.x = w1; o1.y = prev1; o1.z = __sinf(w1); o1.w = __cosf(w1);
    orow[lane] = o0;
    orow[64 + lane] = o1;
}

extern "C" void kernel_launch(void* const* d_in, const int* in_sizes, int n_in,
                              void* d_out, int out_size, void* d_ws, size_t ws_size,
                              hipStream_t stream) {
    const int* char_idx  = (const int*)d_in[0];   // [B*S]
    const int* positions = (const int*)d_in[1];   // [S]
    const float* W       = (const float*)d_in[2]; // [95, 8]
    float* out = (float*)d_out;                   // [B, S, 128, 4]

    const int nrows = in_sizes[0];                // B*S = 65536
    const int S = in_sizes[1];                    // 8192

    float2* tbl = (float2*)d_ws;
    float* pp = (float*)((char*)d_ws + PP_OFF);

    const int build_threads = (NCHARS * ED > S) ? NCHARS * ED : S;
    build_tables<<<(build_threads + 255) / 256, 256, 0, stream>>>(
        positions, W, tbl, pp, S);

    ptok_main<<<nrows / ROWS_PER_BLOCK, 256, 0, stream>>>(
        char_idx, tbl, pp, out, S);
}